// Round 8
// baseline (64.804 us; speedup 1.0000x reference)
//
#include <hip/hip_runtime.h>

#define LN2 0.6931471805599453f

// lane i <- lane i-1 (value), lane 0 <- 0.0f   (wave_shr:1)
__device__ __forceinline__ float dpp_shr1_zero(float x) {
    return __int_as_float(__builtin_amdgcn_update_dpp(
        0, __float_as_int(x), 0x138, 0xF, 0xF, true));
}
// lane i <- lane i-1 (int), lane 0 keeps own
__device__ __forceinline__ int dpp_shr1_keep(int x) {
    return __builtin_amdgcn_update_dpp(x, x, 0x138, 0xF, 0xF, false);
}
// lane i <- lane i+1 (value), lane 63 <- 0.0f  (wave_shl:1)
__device__ __forceinline__ float dpp_shl1_zero(float x) {
    return __int_as_float(__builtin_amdgcn_update_dpp(
        0, __float_as_int(x), 0x130, 0xF, 0xF, true));
}
// lane i <- lane i+1 (int), lane 63 keeps own
__device__ __forceinline__ int dpp_shl1_keep(int x) {
    return __builtin_amdgcn_update_dpp(x, x, 0x130, 0xF, 0xF, false);
}
// exact 2^clamp(d, -126, 127)
__device__ __forceinline__ float exp2i_clamped(int d) {
    int k = 127 + d;
    k = (k < 1) ? 1 : ((k > 254) ? 254 : k);
    return __uint_as_float(((unsigned)k) << 23);
}
__device__ __forceinline__ float sel3(int e, float v0, float v1, float v2) {
    return (e == 2) ? v2 : ((e == 1) ? v1 : v0);
}

struct FwdState {
    float a0, a1, a2;   // alpha (linear, scaled by 2^-esum)
    float s1, k0, k1;   // 2^(eL-e), skm0*s1, skm1*s1
    int   esum;
};
struct BwdState {
    float c0, c1, c2;   // gamma = emit*beta (linear, scaled by 2^-esum)
    float s1b, kA, kB;  // 2^(eR-e), sknA*s1b, sknB*s1b
    int   esum;
};

// 11 VALU per step
__device__ __forceinline__ void fwd_step(float em0, float em1, float em2,
                                         FwdState& st, float skm2) {
    float d2 = dpp_shr1_zero(st.a2);    // alpha[l0-1] (left-neighbor scale)
    float d1 = dpp_shr1_zero(st.a1);    // alpha[l0-2]
    float n0 = fmaf(st.k0, d1, fmaf(st.s1, d2, st.a0)) * em0;
    float n1 = fmaf(st.k1, d2, st.a1 + st.a0) * em1;
    float n2 = fmaf(skm2, st.a0, st.a2 + st.a1) * em2;
    st.a0 = n0; st.a1 = n1; st.a2 = n2;
}
// mirror: gamma_t(l) = e_t(l) * (g(l) + g(l+1) + sk(l+2)*g(l+2)), shifts from right
__device__ __forceinline__ void bwd_step(float em0, float em1, float em2,
                                         BwdState& st, float skm2) {
    float d3 = dpp_shl1_zero(st.c0);    // gamma[l0+3] (right-neighbor scale)
    float d4 = dpp_shl1_zero(st.c1);    // gamma[l0+4]
    float n0 = fmaf(skm2, st.c2, st.c0 + st.c1) * em0;
    float n1 = fmaf(st.kA, d3, st.c1 + st.c2) * em1;
    float n2 = fmaf(st.kB, d4, fmaf(st.s1b, d3, st.c2)) * em2;
    st.c0 = n0; st.c1 = n1; st.c2 = n2;
}

// Fwd rescale every 8 own-steps (unchanged from R6 — proven exact):
__device__ __forceinline__ void fwd_rescale(FwdState& st, float skm0, float skm1) {
    float m = fmaxf(fmaxf(st.a0, st.a1), st.a2);
    int ebits = (int)(__float_as_uint(m) >> 23);
    bool dead = (ebits == 0);
    int de = dead ? 0 : (127 - ebits);
    float scz = dead ? 0.0f : exp2i_clamped(de);
    st.a0 *= scz; st.a1 *= scz; st.a2 *= scz;
    st.esum -= de;
    #pragma unroll
    for (int r = 0; r < 5; ++r) {
        int en = dpp_shr1_keep(st.esum);
        st.esum = dead ? en : st.esum;
    }
    int enf = dpp_shr1_keep(st.esum);
    int gap = enf - st.esum;
    int adj = (gap > 64) ? (gap - 64) : 0;
    float sc3 = exp2i_clamped(-adj);
    st.a0 *= sc3; st.a1 *= sc3; st.a2 *= sc3;
    st.esum += adj;
    st.s1 = exp2i_clamped(gap - adj);
    st.k0 = skm0 * st.s1;
    st.k1 = skm1 * st.s1;
}
// Bwd rescale — R8 hardened. R7's inf: the permanently-dead region (l > 2tl)
// kept esum=0 while live esum declined; the boundary lane's gap grew unbounded,
// exp2i clamped the applied scale but esum used the unclamped delta ->
// representation corruption -> inf. Fixes: (1) left-min adoption keeps dead
// region tracking live esums; (2) adj capped at 126 so scale is ALWAYS the
// exact pow2 matching the esum delta; (3) dead right neighbor => adj=0, s1b=0.
__device__ __forceinline__ void bwd_rescale(BwdState& st, float sknA, float sknB) {
    float m = fmaxf(fmaxf(st.c0, st.c1), st.c2);
    int ebits = (int)(__float_as_uint(m) >> 23);
    bool dead = (ebits == 0);
    int de = dead ? 0 : (127 - ebits);
    float scz = dead ? 0.0f : exp2i_clamped(de);
    st.c0 *= scz; st.c1 *= scz; st.c2 *= scz;
    st.esum -= de;
    // dead lanes adopt right neighbor's esum (frontier side, 5-deep)
    #pragma unroll
    for (int r = 0; r < 5; ++r) {
        int en = dpp_shl1_keep(st.esum);
        st.esum = dead ? en : st.esum;
    }
    // dead lanes also track live region on their LEFT (min, 3-deep)
    #pragma unroll
    for (int r = 0; r < 3; ++r) {
        int enl = dpp_shr1_keep(st.esum);
        int mn = (enl < st.esum) ? enl : st.esum;
        st.esum = dead ? mn : st.esum;
    }
    int deadR = dpp_shl1_keep(dead ? 1 : 0);
    int enf = dpp_shl1_keep(st.esum);
    int gap = enf - st.esum;
    int adj = (gap > 64) ? (gap - 64) : 0;
    adj = (adj > 126) ? 126 : adj;
    adj = deadR ? 0 : adj;              // zero-valued neighbor: no clamp needed
    float sc3 = exp2i_clamped(-adj);    // exact (|adj| <= 126)
    st.c0 *= sc3; st.c1 *= sc3; st.c2 *= sc3;
    st.esum += adj;
    float s1b = exp2i_clamped(gap - adj);
    st.s1b = deadR ? 0.f : s1b;         // kill stale incoming from dead lanes
    st.kA = sknA * st.s1b;
    st.kB = sknB * st.s1b;
}

// One wave per (b,f). Bidirectional: alpha forward + gamma backward interleaved
// (2 independent dependency chains, half the serial depth). Combine at midpoint:
// p = sum_l alpha_m(l) * (g_{m+1}(l) + g_{m+1}(l+1) + sk(l+2) g_{m+1}(l+2)).
__global__ __launch_bounds__(64, 1) void ctc_kernel(
    const float* __restrict__ logits,        // [T, B, 2F+1]
    const int* __restrict__ targets,         // [B, F, S]
    const int* __restrict__ input_lengths,   // [B]
    const int* __restrict__ target_lengths,  // [B, F]
    float* __restrict__ loss_out,            // [B*F] (loss / tl)
    int T, int B, int Ff, int S)
{
    const int p = blockIdx.x;
    const int b = p / Ff;
    const int f = p - b * Ff;
    const int lane = (int)threadIdx.x;
    const int C = 2 * Ff + 1;
    const int L = 2 * S + 1;

    const int tl = target_lengths[p];
    const int il = input_lengths[b];
    const int tbase = p * S;

    // ---- per-lane static metadata: states l = 3*lane + j ----
    int e0i, e1i, e2i;
    float skm0, skm1, skm2;
    {
        int e[3]; float sk[3];
        const int l0 = 3 * lane;
        #pragma unroll
        for (int j = 0; j < 3; ++j) {
            int l = l0 + j;
            int ev = 2; float sok = 0.f;
            if (l < L && (l & 1)) {
                int s = (l - 1) >> 1;
                ev = targets[tbase + s];
                if (s >= 1) sok = (targets[tbase + s - 1] != ev) ? 1.f : 0.f;
            }
            e[j] = ev; sk[j] = sok;
        }
        e0i = e[0]; e1i = e[1]; e2i = e[2];
        skm0 = sk[0]; skm1 = sk[1]; skm2 = sk[2];
    }
    const float sknA = dpp_shl1_zero(skm0);   // skip_ok(l0+3)
    const float sknB = dpp_shl1_zero(skm1);   // skip_ok(l0+4)

    // ---- stage linear softmax into LDS (software-pipelined) ----
    __shared__ float4 slp[608];     // T + pad (zero)
    {
        const float* lg = logits + (size_t)b * C;
        const size_t strideT = (size_t)B * C;
        float c0 = 0.f, c1 = 0.f, c2 = 0.f;
        if (lane < T) {
            const float* r = lg + (size_t)lane * strideT;
            c0 = r[f]; c1 = r[Ff + f]; c2 = r[2 * Ff];
        }
        #pragma unroll 1
        for (int j = 0; j < 10; ++j) {          // 10*64 = 640 >= 608
            int i = lane + (j << 6);
            int inx = i + 64;
            float n0 = 0.f, n1 = 0.f, n2 = 0.f;
            if (inx < T) {
                const float* r = lg + (size_t)inx * strideT;
                n0 = r[f]; n1 = r[Ff + f]; n2 = r[2 * Ff];
            }
            float4 v = make_float4(0.f, 0.f, 0.f, 0.f);
            if (i < T) {
                float m = fmaxf(fmaxf(c0, c1), c2);
                float ep = __expf(c0 - m);
                float en = __expf(c1 - m);
                float eb = __expf(c2 - m);
                float inv = __builtin_amdgcn_rcpf(ep + en + eb);
                v = make_float4(ep * inv, en * inv, eb * inv, 0.f);
            }
            if (i < 608) slp[i] = v;
            c0 = n0; c1 = n1; c2 = n2;
        }
    }
    __syncthreads();

    // per-lane emission base pointers (byte offset e*4 within each 16B row)
    const char* base8 = (const char*)slp;
    const char* qt0 = base8 + (e0i << 2);
    const char* qt1 = base8 + (e1i << 2);
    const char* qt2 = base8 + (e2i << 2);

    const int TL = (il < T) ? il : T;              // frames 0..TL-1
    const int m_ = (TL >= 2) ? ((TL - 1) >> 1) : 0;
    const int Bk = (TL >= 2) ? (TL - 2 - m_) : 0;   // bwd steps (rows TL-2..m_+1)
    const int F  = m_;                              // fwd steps (rows 1..m_)
    const int P  = (F < Bk) ? F : Bk;
    const int nblk = P >> 3;

    // ---- init fwd (frame 0) and bwd (frame TL-1 indicator * emission) ----
    FwdState fs;
    BwdState bs;
    {
        float4 E0 = slp[0];
        fs.a0 = (lane == 0) ? E0.z : 0.f;
        fs.a1 = (lane == 0 && tl > 0) ? sel3(e1i, E0.x, E0.y, E0.z) : 0.f;
        fs.a2 = 0.f;
        fs.s1 = 1.f; fs.k0 = skm0; fs.k1 = skm1;
        fs.esum = 0;

        int oTL = (TL - 1) << 4;
        float eL0 = *(const float*)(qt0 + oTL);
        float eL1 = *(const float*)(qt1 + oTL);
        float eL2 = *(const float*)(qt2 + oTL);
        int l0i = 3 * lane;
        int end1 = 2 * tl, end2 = 2 * tl - 1;
        bs.c0 = (l0i == end1 || l0i == end2) ? eL0 : 0.f;
        bs.c1 = (l0i + 1 == end1 || l0i + 1 == end2) ? eL1 : 0.f;
        bs.c2 = (l0i + 2 == end1 || l0i + 2 == end2) ? eL2 : 0.f;
        bs.s1b = 1.f; bs.kA = sknA; bs.kB = sknB;
        bs.esum = 0;
    }

    // ---- main loop: 8 fwd + 8 bwd steps per block, interleaved ----
    const char* pf0 = qt0 + 16;                 // fwd row 1, ascending
    const char* pf1 = qt1 + 16;
    const char* pf2 = qt2 + 16;
    const char* pb0 = qt0 + ((TL - 2) << 4);    // bwd row TL-2, descending
    const char* pb1 = qt1 + ((TL - 2) << 4);
    const char* pb2 = qt2 + ((TL - 2) << 4);
#define LDF(OFF, E) { E[0] = *(const float*)(pf0 + (OFF)); \
                      E[1] = *(const float*)(pf1 + (OFF)); \
                      E[2] = *(const float*)(pf2 + (OFF)); }
#define LDB(OFF, E) { E[0] = *(const float*)(pb0 - (OFF)); \
                      E[1] = *(const float*)(pb1 - (OFF)); \
                      E[2] = *(const float*)(pb2 - (OFF)); }
    float FA0[3], FA1[3], FA2[3], FA3[3], FB0[3], FB1[3], FB2[3], FB3[3];
    float GA0[3], GA1[3], GA2[3], GA3[3], GB0[3], GB1[3], GB2[3], GB3[3];
    if (nblk > 0) {
        LDF(  0, FA0); LDF( 16, FA1); LDF( 32, FA2); LDF( 48, FA3);
        LDF( 64, FB0); LDF( 80, FB1); LDF( 96, FB2); LDF(112, FB3);
        LDB(  0, GA0); LDB( 16, GA1); LDB( 32, GA2); LDB( 48, GA3);
        LDB( 64, GB0); LDB( 80, GB1); LDB( 96, GB2); LDB(112, GB3);
    }
    for (int blk = 0; blk < nblk; ++blk) {
        fwd_rescale(fs, skm0, skm1);
        bwd_rescale(bs, sknA, sknB);
        fwd_step(FA0[0], FA0[1], FA0[2], fs, skm2);
        bwd_step(GA0[0], GA0[1], GA0[2], bs, skm2);
        fwd_step(FA1[0], FA1[1], FA1[2], fs, skm2);
        bwd_step(GA1[0], GA1[1], GA1[2], bs, skm2);
        fwd_step(FA2[0], FA2[1], FA2[2], fs, skm2);
        bwd_step(GA2[0], GA2[1], GA2[2], bs, skm2);
        fwd_step(FA3[0], FA3[1], FA3[2], fs, skm2);
        bwd_step(GA3[0], GA3[1], GA3[2], bs, skm2);
        LDF(128, FA0); LDF(144, FA1); LDF(160, FA2); LDF(176, FA3);
        LDB(128, GA0); LDB(144, GA1); LDB(160, GA2); LDB(176, GA3);
        fwd_step(FB0[0], FB0[1], FB0[2], fs, skm2);
        bwd_step(GB0[0], GB0[1], GB0[2], bs, skm2);
        fwd_step(FB1[0], FB1[1], FB1[2], fs, skm2);
        bwd_step(GB1[0], GB1[1], GB1[2], bs, skm2);
        fwd_step(FB2[0], FB2[1], FB2[2], fs, skm2);
        bwd_step(GB2[0], GB2[1], GB2[2], bs, skm2);
        fwd_step(FB3[0], FB3[1], FB3[2], fs, skm2);
        bwd_step(GB3[0], GB3[1], GB3[2], bs, skm2);
        LDF(192, FB0); LDF(208, FB1); LDF(224, FB2); LDF(240, FB3);
        LDB(192, GB0); LDB(208, GB1); LDB(224, GB2); LDB(240, GB3);
        pf0 += 128; pf1 += 128; pf2 += 128;
        pb0 -= 128; pb1 -= 128; pb2 -= 128;
    }
#undef LDF
#undef LDB
    // ---- tails (<=7 pairs + remainder), no rescale needed ----
    int tf = 8 * nblk + 1;          // next fwd row
    int tb = TL - 2 - 8 * nblk;     // next bwd row
    while (tf <= F && tb >= m_ + 1) {
        int of = tf << 4, ob = tb << 4;
        float f0 = *(const float*)(qt0 + of);
        float f1 = *(const float*)(qt1 + of);
        float f2 = *(const float*)(qt2 + of);
        float g0 = *(const float*)(qt0 + ob);
        float g1 = *(const float*)(qt1 + ob);
        float g2 = *(const float*)(qt2 + ob);
        fwd_step(f0, f1, f2, fs, skm2);
        bwd_step(g0, g1, g2, bs, skm2);
        ++tf; --tb;
    }
    while (tf <= F) {
        int of = tf << 4;
        float f0 = *(const float*)(qt0 + of);
        float f1 = *(const float*)(qt1 + of);
        float f2 = *(const float*)(qt2 + of);
        fwd_step(f0, f1, f2, fs, skm2);
        ++tf;
    }
    while (tb >= m_ + 1) {
        int ob = tb << 4;
        float g0 = *(const float*)(qt0 + ob);
        float g1 = *(const float*)(qt1 + ob);
        float g2 = *(const float*)(qt2 + ob);
        bwd_step(g0, g1, g2, bs, skm2);
        --tb;
    }

    // ---- epilogue: midpoint combine with exact exponent bookkeeping ----
    __shared__ float sa[192];
    __shared__ float sg[194];
    __shared__ int   seb[65];
    __shared__ float sdot[64];
    __shared__ int   sE[64];
    {
        int l0b = 3 * lane;
        sa[l0b] = fs.a0; sa[l0b + 1] = fs.a1; sa[l0b + 2] = fs.a2;
        sg[l0b] = bs.c0; sg[l0b + 1] = bs.c1; sg[l0b + 2] = bs.c2;
        seb[lane] = bs.esum;
        if (lane == 0) { sg[192] = 0.f; sg[193] = 0.f; seb[64] = 0; }
    }
    __syncthreads();
    {
        // align right lane's gamma into our scale (0-valued when right is dead,
        // so a clamped scn can never produce a wrong nonzero term)
        float scn = exp2i_clamped(seb[lane + 1] - bs.esum);
        float g3 = sg[3 * lane + 3] * scn;
        float g4 = sg[3 * lane + 4] * scn;
        float s0 = fmaf(skm2, bs.c2, bs.c0 + bs.c1);
        float s1 = fmaf(sknA, g3, bs.c1 + bs.c2);
        float s2 = fmaf(sknB, g4, bs.c2 + g3);
        float dot = fs.a0 * s0 + fs.a1 * s1 + fs.a2 * s2;
        sdot[lane] = dot;
        sE[lane] = fs.esum + bs.esum;
    }
    __syncthreads();
    if (lane == 0) {
        float loss = 0.f;
        if (TL == 1) {
            float v = sa[2 * tl] + ((tl > 0) ? sa[2 * tl - 1] : 0.f);
            if (v > 0.f) loss = -(__log2f(v) * LN2);
        } else {
            int Emax = -0x40000000;
            for (int i = 0; i < 64; ++i)
                if (sdot[i] > 0.f && sE[i] > Emax) Emax = sE[i];
            if (Emax != -0x40000000) {
                float sum = 0.f;
                for (int i = 0; i < 64; ++i) {
                    int d = sE[i] - Emax;
                    if (d > -127 && sdot[i] > 0.f) sum += sdot[i] * exp2i_clamped(d);
                }
                loss = -((__log2f(sum) + (float)Emax) * LN2);
            }
        }
        float denom = (tl > 0) ? (float)tl : 1.0f;
        loss_out[p] = loss / denom;
    }
}

// Deterministic single-block reduction: out[0] = sum(v) / B
__global__ __launch_bounds__(256) void reduce_kernel(
    const float* __restrict__ v, float* __restrict__ out, int n, float invB)
{
    __shared__ float buf[256];
    float s = 0.f;
    for (int i = (int)threadIdx.x; i < n; i += 256) s += v[i];
    buf[threadIdx.x] = s;
    __syncthreads();
    for (int off = 128; off > 0; off >>= 1) {
        if ((int)threadIdx.x < off) buf[threadIdx.x] += buf[threadIdx.x + off];
        __syncthreads();
    }
    if (threadIdx.x == 0) out[0] = buf[0] * invB;
}

extern "C" void kernel_launch(void* const* d_in, const int* in_sizes, int n_in,
                              void* d_out, int out_size, void* d_ws, size_t ws_size,
                              hipStream_t stream) {
    const float* logits         = (const float*)d_in[0];
    const int*   targets        = (const int*)d_in[1];
    const int*   input_lengths  = (const int*)d_in[2];
    const int*   target_lengths = (const int*)d_in[3];
    float* out = (float*)d_out;

    const int B  = in_sizes[2];            // 32
    const int BF = in_sizes[3];            // B*F = 1120
    const int Ff = BF / B;                 // 35
    const int S  = in_sizes[1] / BF;       // 80
    const int C  = 2 * Ff + 1;             // 71
    const int T  = in_sizes[0] / (B * C);  // 600

    float* losses = (float*)d_ws;          // BF floats of scratch

    ctc_kernel<<<BF, 64, 0, stream>>>(logits, targets, input_lengths,
                                      target_lengths, losses, T, B, Ff, S);
    reduce_kernel<<<1, 256, 0, stream>>>(losses, out, BF, 1.0f / (float)B);
}